// Round 1
// baseline (700.721 us; speedup 1.0000x reference)
//
#include <hip/hip_runtime.h>

// out[b,g,h,w] = sum_n x[b, IDX[g,n], h, w] * w[g,n]
// IDX[g,n] = (g/4)*16 + n*4 + (g%4)   (bijection over 64 channels)
// B=8, C=64, G=16, N=4, HW=512*512.
// Pure streaming: 512 MiB read + 128 MiB write -> HBM-bound, ~107 us roofline.

#define B_  8
#define C_  64
#define G_  16
#define HW_ 262144    // 512*512
#define HW4_ 65536    // HW_/4 (float4 units)

__global__ __launch_bounds__(256) void binnings_kernel(
    const float4* __restrict__ x,     // (B, C, HW4) in float4 units
    const float4* __restrict__ w4,    // (G) : w4[g] = (w[g,0..3])
    float4* __restrict__ out)         // (B, G, HW4)
{
    const int tid = blockIdx.x * blockDim.x + threadIdx.x;  // [0, B*G*HW4)
    const int hw4 = tid & (HW4_ - 1);
    const int bg  = tid >> 16;        // tid / HW4_
    const int g   = bg & (G_ - 1);
    const int b   = bg >> 4;

    // base input channel for this g; the 4 summed channels are base+4n
    const int c0 = ((g >> 2) << 4) + (g & 3);

    const float4 w = w4[g];

    const size_t xbase = ((size_t)(b * C_ + c0)) * HW4_ + hw4;
    const float4 a0 = x[xbase];
    const float4 a1 = x[xbase + (size_t)4  * HW4_];
    const float4 a2 = x[xbase + (size_t)8  * HW4_];
    const float4 a3 = x[xbase + (size_t)12 * HW4_];

    float4 o;
    o.x = a0.x * w.x + a1.x * w.y + a2.x * w.z + a3.x * w.w;
    o.y = a0.y * w.x + a1.y * w.y + a2.y * w.z + a3.y * w.w;
    o.z = a0.z * w.x + a1.z * w.y + a2.z * w.z + a3.z * w.w;
    o.w = a0.w * w.x + a1.w * w.y + a2.w * w.z + a3.w * w.w;

    out[(size_t)bg * HW4_ + hw4] = o;
}

extern "C" void kernel_launch(void* const* d_in, const int* in_sizes, int n_in,
                              void* d_out, int out_size, void* d_ws, size_t ws_size,
                              hipStream_t stream) {
    const float4* x  = (const float4*)d_in[0];   // (8,64,512,512) f32
    const float4* w4 = (const float4*)d_in[1];   // (16,4,1,1) f32
    float4* out = (float4*)d_out;                // (8,16,512,512) f32

    const int total = B_ * G_ * HW4_;            // 8,388,608 threads
    const int block = 256;
    const int grid = total / block;              // 32768 blocks
    binnings_kernel<<<grid, block, 0, stream>>>(x, w4, out);
}